// Round 6
// baseline (598.004 us; speedup 1.0000x reference)
//
#include <hip/hip_runtime.h>
#include <stdint.h>

#define VOCAB 50257
#define EMBED 512
#define HIDDEN 1024
#define BATCH 4096
#define SEQ 16

typedef __attribute__((ext_vector_type(8))) short short8;
typedef __attribute__((ext_vector_type(4))) float f32x4;
typedef __attribute__((ext_vector_type(4))) int int4v;
typedef __attribute__((ext_vector_type(4))) float float4v;

__device__ __forceinline__ uint32_t f2bfu(float f) {
  uint32_t u = __builtin_bit_cast(uint32_t, f);
  return (u + 0x7FFFu + ((u >> 16) & 1u)) >> 16;  // RNE f32 -> bf16
}

__device__ __forceinline__ int4v pack8(float4v a, float4v b) {
  int4v r;
  r.x = (int)(f2bfu(a.x) | (f2bfu(a.y) << 16));
  r.y = (int)(f2bfu(a.z) | (f2bfu(a.w) << 16));
  r.z = (int)(f2bfu(b.x) | (f2bfu(b.y) << 16));
  r.w = (int)(f2bfu(b.z) | (f2bfu(b.w) << 16));
  return r;
}

__device__ __forceinline__ void gload16(const void* g, void* l) {
  __builtin_amdgcn_global_load_lds((const __attribute__((address_space(1))) void*)g,
                                   (__attribute__((address_space(3))) void*)l,
                                   16, 0, 0);
}

// ---------- prep: emb fp32 -> bf16 ----------
__global__ void prep_emb_k(const float* __restrict__ emb, ushort* __restrict__ dst, int n8) {
  int i = blockIdx.x * 256 + threadIdx.x;
  if (i >= n8) return;
  size_t e = (size_t)i * 8;
  float4v a = *(const float4v*)(emb + e);
  float4v b = *(const float4v*)(emb + e + 4);
  *(int4v*)(dst + e) = pack8(a, b);
}

// ---------- prep: weights -> bf16, Wkv=[WK;WV], Wqv=[WQ;WV] ----------
__global__ void prep_w_k(const float* __restrict__ WQ, const float* __restrict__ WK,
                         const float* __restrict__ WV, ushort* __restrict__ Wkv,
                         ushort* __restrict__ Wqv) {
  int i = blockIdx.x * 256 + threadIdx.x;  // 0..262143
  int which = i >> 17;                     // 0 -> Wkv, 1 -> Wqv
  int j = i & 0x1FFFF;
  size_t e = (size_t)j * 8;
  int row = (int)(e >> 9);
  int col = (int)(e & 511);
  const float* src = (which == 0)
      ? ((row < 1024) ? WK + (size_t)row * 512 + col : WV + (size_t)(row - 1024) * 512 + col)
      : ((row < 1024) ? WQ + (size_t)row * 512 + col : WV + (size_t)(row - 1024) * 512 + col);
  float4v a = *(const float4v*)(src);
  float4v b = *(const float4v*)(src + 4);
  ushort* dst = (which == 0) ? Wkv : Wqv;
  *(int4v*)(dst + e) = pack8(a, b);
}

// ---------- GEMM: C[m,n] = sum_k embb[tok[m],k] * W[n,k] + bias[n] ----------
// 128x128 tile, BK=32, 4 waves (2x2), each wave 64x64 (4x4 frags of 16x16).
// EPI=0 (ctx): n<1024 -> K_buf bf16 row-major; n>=1024 -> V_buf bf16 in
//              B-frag-ready layout off = (d/16)*256 + (g/8)*128 + (d%16)*8 + (g%8)
// EPI=1 (tgt): n<1024 -> Q_buf bf16; n>=1024 -> out0 fp32 (target_vector)
template <int EPI>
__global__ __launch_bounds__(256) void gemm_k(
    const ushort* __restrict__ Aemb, const int* __restrict__ tok,
    const ushort* __restrict__ W, const float* __restrict__ bias_lo,
    const float* __restrict__ bias_hi, ushort* __restrict__ out_lo,
    void* __restrict__ out_hi_) {
  __shared__ ushort At[128 * 32];
  __shared__ ushort Bt[128 * 32];
  const int t = threadIdx.x;
  const int wave = t >> 6, lane = t & 63;
  const int mb = blockIdx.x, nb = blockIdx.y;
  const int r0 = t >> 2;
  const int acol = (t & 3) * 8;
  const int tok0 = tok[mb * 128 + r0];
  const int tok1 = tok[mb * 128 + 64 + r0];
  const ushort* asrc0 = Aemb + (size_t)tok0 * EMBED + acol;
  const ushort* asrc1 = Aemb + (size_t)tok1 * EMBED + acol;
  const ushort* bsrc0 = W + (size_t)(nb * 128 + r0) * EMBED + acol;
  const ushort* bsrc1 = W + (size_t)(nb * 128 + 64 + r0) * EMBED + acol;
  char* aD0 = (char*)At + wave * 1024;
  char* aD1 = (char*)At + 4096 + wave * 1024;
  char* bD0 = (char*)Bt + wave * 1024;
  char* bD1 = (char*)Bt + 4096 + wave * 1024;
  const int wm = wave >> 1, wn = wave & 1;
  const int fr = lane & 15, fu = lane >> 4;
  f32x4 acc[4][4] = {};
  for (int kt = 0; kt < 16; ++kt) {
    const int k0 = kt * 32;
    gload16(asrc0 + k0, aD0);
    gload16(asrc1 + k0, aD1);
    gload16(bsrc0 + k0, bD0);
    gload16(bsrc1 + k0, bD1);
    __syncthreads();
    short8 af[4], bf[4];
#pragma unroll
    for (int mi = 0; mi < 4; ++mi)
      af[mi] = *(const short8*)(At + (wm * 64 + mi * 16 + fr) * 32 + fu * 8);
#pragma unroll
    for (int ni = 0; ni < 4; ++ni)
      bf[ni] = *(const short8*)(Bt + (wn * 64 + ni * 16 + fr) * 32 + fu * 8);
#pragma unroll
    for (int mi = 0; mi < 4; ++mi)
#pragma unroll
      for (int ni = 0; ni < 4; ++ni)
        acc[mi][ni] = __builtin_amdgcn_mfma_f32_16x16x32_bf16(af[mi], bf[ni], acc[mi][ni], 0, 0, 0);
    __syncthreads();
  }
  // ---- epilogue ----
#pragma unroll
  for (int ni = 0; ni < 4; ++ni) {
    const int nloc = nb * 128 + wn * 64 + ni * 16 + fr;  // 0..2047
    if (nb < 8) {
      const float bv = bias_lo[nloc];
#pragma unroll
      for (int mi = 0; mi < 4; ++mi)
#pragma unroll
        for (int r = 0; r < 4; ++r) {
          const int m = mb * 128 + wm * 64 + mi * 16 + fu * 4 + r;
          out_lo[(size_t)m * 1024 + nloc] = (ushort)f2bfu(acc[mi][ni][r] + bv);
        }
    } else {
      const int n = nloc - 1024;
      const float bv = bias_hi[n];
      if (EPI == 0) {
        ushort* Vb = (ushort*)out_hi_;
        const int g = n >> 6, d = n & 63;
        const int offv = (d >> 4) * 256 + (g >> 3) * 128 + (d & 15) * 8 + (g & 7);
#pragma unroll
        for (int mi = 0; mi < 4; ++mi)
#pragma unroll
          for (int r = 0; r < 4; ++r) {
            const int m = mb * 128 + wm * 64 + mi * 16 + fu * 4 + r;
            Vb[(size_t)m * 1024 + offv] = (ushort)f2bfu(acc[mi][ni][r] + bv);
          }
      } else {
        float* o0 = (float*)out_hi_;
#pragma unroll
        for (int mi = 0; mi < 4; ++mi)
#pragma unroll
          for (int r = 0; r < 4; ++r) {
            const int m = mb * 128 + wm * 64 + mi * 16 + fu * 4 + r;
            o0[(size_t)m * 1024 + n] = acc[mi][ni][r] + bv;
          }
      }
    }
  }
}

// ---------- attention: one wave per batch element ----------
// D1[g][h] = sum_d K_s[g][d] * Q[h][d]  (swapped so softmax over g is
// 4 in-lane regs + shfl_xor(16) + shfl_xor(32)). Softmaxed P is then already
// in the PV A-operand layout (A[h][g], h=lane%16, g=4*(lane/16)+e) after a
// 4x ds_bpermute cross-group redistribution; k=16..31 of the K=32 MFMA is
// zeroed. V fragments load directly from the permuted V_buf (coalesced 16B).
__global__ __launch_bounds__(256) void attn_k(const ushort* __restrict__ Qb,
                                              const ushort* __restrict__ Kb,
                                              const ushort* __restrict__ Vb,
                                              float* __restrict__ out1) {
  const int wave = threadIdx.x >> 6, lane = threadIdx.x & 63;
  const int b = blockIdx.x * 4 + wave;
  const int u = lane >> 4, col = lane & 15;
  const ushort* qrow = Qb + (size_t)b * 1024;
  const short8 qf0 = *(const short8*)(qrow + col * 64 + u * 8);
  const short8 qf1 = *(const short8*)(qrow + col * 64 + u * 8 + 32);
  f32x4 accd[4] = {};
  const int srcA = (col + ((u & 1) << 5)) << 2;  // bpermute byte addr
  for (int s = 0; s < 16; ++s) {
    const size_t m = (size_t)b * 16 + s;
    const ushort* krow = Kb + m * 1024;
    const short8 kf0 = *(const short8*)(krow + col * 64 + u * 8);
    const short8 kf1 = *(const short8*)(krow + col * 64 + u * 8 + 32);
    f32x4 sc = {};
    sc = __builtin_amdgcn_mfma_f32_16x16x32_bf16(kf0, qf0, sc, 0, 0, 0);
    sc = __builtin_amdgcn_mfma_f32_16x16x32_bf16(kf1, qf1, sc, 0, 0, 0);
    float x0 = sc[0] * 0.125f, x1 = sc[1] * 0.125f;
    float x2 = sc[2] * 0.125f, x3 = sc[3] * 0.125f;
    float mx = fmaxf(fmaxf(x0, x1), fmaxf(x2, x3));
    mx = fmaxf(mx, __shfl_xor(mx, 16));
    mx = fmaxf(mx, __shfl_xor(mx, 32));
    float p0 = __expf(x0 - mx), p1 = __expf(x1 - mx);
    float p2 = __expf(x2 - mx), p3 = __expf(x3 - mx);
    float sm = p0 + p1 + p2 + p3;
    sm += __shfl_xor(sm, 16);
    sm += __shfl_xor(sm, 32);
    const float inv = 1.0f / sm;
    const uint32_t w01 = f2bfu(p0 * inv) | (f2bfu(p1 * inv) << 16);
    const uint32_t w23 = f2bfu(p2 * inv) | (f2bfu(p3 * inv) << 16);
    int d0 = __builtin_amdgcn_ds_bpermute(srcA, (int)w01);
    int d1 = __builtin_amdgcn_ds_bpermute(srcA, (int)w23);
    int d2 = __builtin_amdgcn_ds_bpermute(srcA + 64, (int)w01);
    int d3 = __builtin_amdgcn_ds_bpermute(srcA + 64, (int)w23);
    if (lane >= 32) { d0 = 0; d1 = 0; d2 = 0; d3 = 0; }
    int4v ww;
    ww.x = d0; ww.y = d1; ww.z = d2; ww.w = d3;
    const short8 af = __builtin_bit_cast(short8, ww);
    const ushort* vrow = Vb + m * 1024;
#pragma unroll
    for (int dblk = 0; dblk < 4; ++dblk) {
      const short8 vf = *(const short8*)(vrow + dblk * 256 + (u & 1) * 128 + col * 8);
      accd[dblk] = __builtin_amdgcn_mfma_f32_16x16x32_bf16(af, vf, accd[dblk], 0, 0, 0);
    }
  }
  float* orow = out1 + (size_t)b * 1024;
#pragma unroll
  for (int dblk = 0; dblk < 4; ++dblk)
#pragma unroll
    for (int r = 0; r < 4; ++r)
      orow[(u * 4 + r) * 64 + dblk * 16 + col] = accd[dblk][r];
}

extern "C" void kernel_launch(void* const* d_in, const int* in_sizes, int n_in,
                              void* d_out, int out_size, void* d_ws, size_t ws_size,
                              hipStream_t stream) {
  (void)in_sizes; (void)n_in; (void)out_size; (void)ws_size;
  const int* t = (const int*)d_in[0];
  const int* c = (const int*)d_in[1];
  const float* emb = (const float*)d_in[2];
  const float* WQ = (const float*)d_in[3];
  const float* bQ = (const float*)d_in[4];
  const float* WK = (const float*)d_in[5];
  const float* bK = (const float*)d_in[6];
  const float* WV = (const float*)d_in[7];
  const float* bV = (const float*)d_in[8];
  float* out0 = (float*)d_out;                       // target_vector [4096][1024]
  float* out1 = out0 + (size_t)BATCH * HIDDEN;       // context_vector

  char* ws = (char*)d_ws;
  size_t off = 0;
  ushort* embb = (ushort*)(ws + off);
  off += ((size_t)VOCAB * EMBED * 2 + 255) & ~(size_t)255;
  ushort* Wkv = (ushort*)(ws + off); off += (size_t)2048 * 512 * 2;
  ushort* Wqv = (ushort*)(ws + off); off += (size_t)2048 * 512 * 2;
  ushort* Qb = (ushort*)(ws + off); off += (size_t)BATCH * HIDDEN * 2;
  ushort* Kb = (ushort*)(ws + off); off += (size_t)BATCH * SEQ * HIDDEN * 2;
  ushort* Vb = (ushort*)(ws + off); off += (size_t)BATCH * SEQ * HIDDEN * 2;

  const int n8 = VOCAB * EMBED / 8;
  prep_emb_k<<<(n8 + 255) / 256, 256, 0, stream>>>(emb, embb, n8);
  prep_w_k<<<1024, 256, 0, stream>>>(WQ, WK, WV, Wkv, Wqv);
  dim3 gc(BATCH * SEQ / 128, 16);  // 512 x 16
  gemm_k<0><<<gc, 256, 0, stream>>>(embb, c, Wkv, bK, bV, Kb, (void*)Vb);
  dim3 gt(BATCH / 128, 16);        // 32 x 16
  gemm_k<1><<<gt, 256, 0, stream>>>(embb, t, Wqv, bQ, bV, Qb, (void*)out0);
  attn_k<<<BATCH / 4, 256, 0, stream>>>(Qb, Kb, Vb, out1);
}

// Round 12
// 587.333 us; speedup vs baseline: 1.0182x; 1.0182x over previous
//
#include <hip/hip_runtime.h>
#include <stdint.h>

#define VOCAB 50257
#define EMBED 512
#define HIDDEN 1024
#define BATCH 4096
#define SEQ 16

typedef __attribute__((ext_vector_type(8))) short short8;
typedef __attribute__((ext_vector_type(4))) float f32x4;
typedef __attribute__((ext_vector_type(4))) int int4v;
typedef __attribute__((ext_vector_type(4))) float float4v;

__device__ __forceinline__ uint32_t f2bfu(float f) {
  uint32_t u = __builtin_bit_cast(uint32_t, f);
  return (u + 0x7FFFu + ((u >> 16) & 1u)) >> 16;  // RNE f32 -> bf16
}

__device__ __forceinline__ int4v pack8(float4v a, float4v b) {
  int4v r;
  r.x = (int)(f2bfu(a.x) | (f2bfu(a.y) << 16));
  r.y = (int)(f2bfu(a.z) | (f2bfu(a.w) << 16));
  r.z = (int)(f2bfu(b.x) | (f2bfu(b.y) << 16));
  r.w = (int)(f2bfu(b.z) | (f2bfu(b.w) << 16));
  return r;
}

__device__ __forceinline__ void gload16(const void* g, void* l) {
  __builtin_amdgcn_global_load_lds((const __attribute__((address_space(1))) void*)g,
                                   (__attribute__((address_space(3))) void*)l,
                                   16, 0, 0);
}

// ---------- prep: emb fp32 -> bf16 ----------
__global__ void prep_emb_k(const float* __restrict__ emb, ushort* __restrict__ dst, int n8) {
  int i = blockIdx.x * 256 + threadIdx.x;
  if (i >= n8) return;
  size_t e = (size_t)i * 8;
  float4v a = *(const float4v*)(emb + e);
  float4v b = *(const float4v*)(emb + e + 4);
  *(int4v*)(dst + e) = pack8(a, b);
}

// ---------- prep: weights -> bf16, Wkv=[WK;WV], Wqv=[WQ;WV] ----------
__global__ void prep_w_k(const float* __restrict__ WQ, const float* __restrict__ WK,
                         const float* __restrict__ WV, ushort* __restrict__ Wkv,
                         ushort* __restrict__ Wqv) {
  int i = blockIdx.x * 256 + threadIdx.x;  // 0..262143
  int which = i >> 17;                     // 0 -> Wkv, 1 -> Wqv
  int j = i & 0x1FFFF;
  size_t e = (size_t)j * 8;
  int row = (int)(e >> 9);
  int col = (int)(e & 511);
  const float* src = (which == 0)
      ? ((row < 1024) ? WK + (size_t)row * 512 + col : WV + (size_t)(row - 1024) * 512 + col)
      : ((row < 1024) ? WQ + (size_t)row * 512 + col : WV + (size_t)(row - 1024) * 512 + col);
  float4v a = *(const float4v*)(src);
  float4v b = *(const float4v*)(src + 4);
  ushort* dst = (which == 0) ? Wkv : Wqv;
  *(int4v*)(dst + e) = pack8(a, b);
}

// ---------- GEMM: C[m,n] = sum_k embb[tok[m],k] * W[n,k] + bias[n] ----------
// 128x128 tile, BK=32, 4 waves (2x2), each wave 64x64 (4x4 frags of 16x16).
// Grid: x = nb (FAST, 16) so all column-blocks of one row-panel run
// back-to-back -> A-gather served from L2/L3, V-write partial lines merge.
// Double-buffered LDS, 2-phase order: STAGE(next) -> compute(cur) -> sync.
// EPI=0 (ctx): n<1024 -> K_buf bf16 row-major; n>=1024 -> V_buf bf16 in
//              B-frag-ready layout off = (d/16)*256 + (g/8)*128 + (d%16)*8 + (g%8)
// EPI=1 (tgt): n<1024 -> Q_buf bf16; n>=1024 -> out0 fp32 (target_vector)
template <int EPI>
__global__ __launch_bounds__(256) void gemm_k(
    const ushort* __restrict__ Aemb, const int* __restrict__ tok,
    const ushort* __restrict__ W, const float* __restrict__ bias_lo,
    const float* __restrict__ bias_hi, ushort* __restrict__ out_lo,
    void* __restrict__ out_hi_) {
  __shared__ ushort At[2 * 128 * 32];
  __shared__ ushort Bt[2 * 128 * 32];
  const int t = threadIdx.x;
  const int wave = t >> 6, lane = t & 63;
  const int nb = blockIdx.x, mb = blockIdx.y;  // nb is the fast grid axis
  const int r0 = t >> 2;
  const int acol = (t & 3) * 8;
  const int tok0 = tok[mb * 128 + r0];
  const int tok1 = tok[mb * 128 + 64 + r0];
  const ushort* asrc0 = Aemb + (size_t)tok0 * EMBED + acol;
  const ushort* asrc1 = Aemb + (size_t)tok1 * EMBED + acol;
  const ushort* bsrc0 = W + (size_t)(nb * 128 + r0) * EMBED + acol;
  const ushort* bsrc1 = W + (size_t)(nb * 128 + 64 + r0) * EMBED + acol;
  const int wm = wave >> 1, wn = wave & 1;
  const int fr = lane & 15, fu = lane >> 4;

  auto stage = [&](int buf, int kt) {
    const int k0 = kt * 32;
    char* ab = (char*)At + buf * 8192 + wave * 1024;
    char* bb = (char*)Bt + buf * 8192 + wave * 1024;
    gload16(asrc0 + k0, ab);
    gload16(asrc1 + k0, ab + 4096);
    gload16(bsrc0 + k0, bb);
    gload16(bsrc1 + k0, bb + 4096);
  };

  f32x4 acc[4][4] = {};
  stage(0, 0);
  __syncthreads();
  int cur = 0;
  for (int kt = 0; kt < 16; ++kt) {
    if (kt < 15) stage(cur ^ 1, kt + 1);  // loads in flight during compute
    const ushort* Ab = At + cur * 4096;
    const ushort* Bb = Bt + cur * 4096;
    short8 af[4], bf[4];
#pragma unroll
    for (int mi = 0; mi < 4; ++mi)
      af[mi] = *(const short8*)(Ab + (wm * 64 + mi * 16 + fr) * 32 + fu * 8);
#pragma unroll
    for (int ni = 0; ni < 4; ++ni)
      bf[ni] = *(const short8*)(Bb + (wn * 64 + ni * 16 + fr) * 32 + fu * 8);
#pragma unroll
    for (int mi = 0; mi < 4; ++mi)
#pragma unroll
      for (int ni = 0; ni < 4; ++ni)
        acc[mi][ni] = __builtin_amdgcn_mfma_f32_16x16x32_bf16(af[mi], bf[ni], acc[mi][ni], 0, 0, 0);
    __syncthreads();  // drains next-tile loads (vmcnt0) after compute overlap
    cur ^= 1;
  }
  // ---- epilogue ----
#pragma unroll
  for (int ni = 0; ni < 4; ++ni) {
    const int nloc = nb * 128 + wn * 64 + ni * 16 + fr;  // 0..2047
    if (nb < 8) {
      const float bv = bias_lo[nloc];
#pragma unroll
      for (int mi = 0; mi < 4; ++mi)
#pragma unroll
        for (int r = 0; r < 4; ++r) {
          const int m = mb * 128 + wm * 64 + mi * 16 + fu * 4 + r;
          out_lo[(size_t)m * 1024 + nloc] = (ushort)f2bfu(acc[mi][ni][r] + bv);
        }
    } else {
      const int n = nloc - 1024;
      const float bv = bias_hi[n];
      if (EPI == 0) {
        ushort* Vb = (ushort*)out_hi_;
        const int g = n >> 6, d = n & 63;
        const int offv = (d >> 4) * 256 + (g >> 3) * 128 + (d & 15) * 8 + (g & 7);
#pragma unroll
        for (int mi = 0; mi < 4; ++mi)
#pragma unroll
          for (int r = 0; r < 4; ++r) {
            const int m = mb * 128 + wm * 64 + mi * 16 + fu * 4 + r;
            Vb[(size_t)m * 1024 + offv] = (ushort)f2bfu(acc[mi][ni][r] + bv);
          }
      } else {
        float* o0 = (float*)out_hi_;
#pragma unroll
        for (int mi = 0; mi < 4; ++mi)
#pragma unroll
          for (int r = 0; r < 4; ++r) {
            const int m = mb * 128 + wm * 64 + mi * 16 + fu * 4 + r;
            o0[(size_t)m * 1024 + n] = acc[mi][ni][r] + bv;
          }
      }
    }
  }
}

// ---------- attention: one wave per batch element ----------
__global__ __launch_bounds__(256) void attn_k(const ushort* __restrict__ Qb,
                                              const ushort* __restrict__ Kb,
                                              const ushort* __restrict__ Vb,
                                              float* __restrict__ out1) {
  const int wave = threadIdx.x >> 6, lane = threadIdx.x & 63;
  const int b = blockIdx.x * 4 + wave;
  const int u = lane >> 4, col = lane & 15;
  const ushort* qrow = Qb + (size_t)b * 1024;
  const short8 qf0 = *(const short8*)(qrow + col * 64 + u * 8);
  const short8 qf1 = *(const short8*)(qrow + col * 64 + u * 8 + 32);
  f32x4 accd[4] = {};
  const int srcA = (col + ((u & 1) << 5)) << 2;  // bpermute byte addr
  for (int s = 0; s < 16; ++s) {
    const size_t m = (size_t)b * 16 + s;
    const ushort* krow = Kb + m * 1024;
    const short8 kf0 = *(const short8*)(krow + col * 64 + u * 8);
    const short8 kf1 = *(const short8*)(krow + col * 64 + u * 8 + 32);
    f32x4 sc = {};
    sc = __builtin_amdgcn_mfma_f32_16x16x32_bf16(kf0, qf0, sc, 0, 0, 0);
    sc = __builtin_amdgcn_mfma_f32_16x16x32_bf16(kf1, qf1, sc, 0, 0, 0);
    float x0 = sc[0] * 0.125f, x1 = sc[1] * 0.125f;
    float x2 = sc[2] * 0.125f, x3 = sc[3] * 0.125f;
    float mx = fmaxf(fmaxf(x0, x1), fmaxf(x2, x3));
    mx = fmaxf(mx, __shfl_xor(mx, 16));
    mx = fmaxf(mx, __shfl_xor(mx, 32));
    float p0 = __expf(x0 - mx), p1 = __expf(x1 - mx);
    float p2 = __expf(x2 - mx), p3 = __expf(x3 - mx);
    float sm = p0 + p1 + p2 + p3;
    sm += __shfl_xor(sm, 16);
    sm += __shfl_xor(sm, 32);
    const float inv = 1.0f / sm;
    const uint32_t w01 = f2bfu(p0 * inv) | (f2bfu(p1 * inv) << 16);
    const uint32_t w23 = f2bfu(p2 * inv) | (f2bfu(p3 * inv) << 16);
    int d0 = __builtin_amdgcn_ds_bpermute(srcA, (int)w01);
    int d1 = __builtin_amdgcn_ds_bpermute(srcA, (int)w23);
    int d2 = __builtin_amdgcn_ds_bpermute(srcA + 64, (int)w01);
    int d3 = __builtin_amdgcn_ds_bpermute(srcA + 64, (int)w23);
    if (lane >= 32) { d0 = 0; d1 = 0; d2 = 0; d3 = 0; }
    int4v ww;
    ww.x = d0; ww.y = d1; ww.z = d2; ww.w = d3;
    const short8 af = __builtin_bit_cast(short8, ww);
    const ushort* vrow = Vb + m * 1024;
#pragma unroll
    for (int dblk = 0; dblk < 4; ++dblk) {
      const short8 vf = *(const short8*)(vrow + dblk * 256 + (u & 1) * 128 + col * 8);
      accd[dblk] = __builtin_amdgcn_mfma_f32_16x16x32_bf16(af, vf, accd[dblk], 0, 0, 0);
    }
  }
  float* orow = out1 + (size_t)b * 1024;
#pragma unroll
  for (int dblk = 0; dblk < 4; ++dblk)
#pragma unroll
    for (int r = 0; r < 4; ++r)
      orow[(u * 4 + r) * 64 + dblk * 16 + col] = accd[dblk][r];
}

extern "C" void kernel_launch(void* const* d_in, const int* in_sizes, int n_in,
                              void* d_out, int out_size, void* d_ws, size_t ws_size,
                              hipStream_t stream) {
  (void)in_sizes; (void)n_in; (void)out_size; (void)ws_size;
  const int* t = (const int*)d_in[0];
  const int* c = (const int*)d_in[1];
  const float* emb = (const float*)d_in[2];
  const float* WQ = (const float*)d_in[3];
  const float* bQ = (const float*)d_in[4];
  const float* WK = (const float*)d_in[5];
  const float* bK = (const float*)d_in[6];
  const float* WV = (const float*)d_in[7];
  const float* bV = (const float*)d_in[8];
  float* out0 = (float*)d_out;                       // target_vector [4096][1024]
  float* out1 = out0 + (size_t)BATCH * HIDDEN;       // context_vector

  char* ws = (char*)d_ws;
  size_t off = 0;
  ushort* embb = (ushort*)(ws + off);
  off += ((size_t)VOCAB * EMBED * 2 + 255) & ~(size_t)255;
  ushort* Wkv = (ushort*)(ws + off); off += (size_t)2048 * 512 * 2;
  ushort* Wqv = (ushort*)(ws + off); off += (size_t)2048 * 512 * 2;
  ushort* Qb = (ushort*)(ws + off); off += (size_t)BATCH * HIDDEN * 2;
  ushort* Kb = (ushort*)(ws + off); off += (size_t)BATCH * SEQ * HIDDEN * 2;
  ushort* Vb = (ushort*)(ws + off); off += (size_t)BATCH * SEQ * HIDDEN * 2;

  const int n8 = VOCAB * EMBED / 8;
  prep_emb_k<<<(n8 + 255) / 256, 256, 0, stream>>>(emb, embb, n8);
  prep_w_k<<<1024, 256, 0, stream>>>(WQ, WK, WV, Wkv, Wqv);
  dim3 gc(16, BATCH * SEQ / 128);  // x = nb (fast), y = mb
  gemm_k<0><<<gc, 256, 0, stream>>>(embb, c, Wkv, bK, bV, Kb, (void*)Vb);
  dim3 gt(16, BATCH / 128);
  gemm_k<1><<<gt, 256, 0, stream>>>(embb, t, Wqv, bQ, bV, Qb, (void*)out0);
  attn_k<<<BATCH / 4, 256, 0, stream>>>(Qb, Kb, Vb, out1);
}